// Round 9
// baseline (387.012 us; speedup 1.0000x reference)
//
#include <hip/hip_runtime.h>

// Chamfer distance, exact, capped outward walk + brute-force cleanup pass.
//
// R8 post-mortem: walk 79us, VALUBusy 36%, occ 20% -> (1) tail imbalance
// (y-z outliers' waves walk ~half the cloud), (2) 7-op/pair math + 100-op
// per-k butterfly exit test. R9: (a) expansion form u = |q|^2 - 2p.q ->
// 4 ops/pair (|p|^2 folded out, added at exit); (b) exit test butterflies one
// scalar U = max_k(cm_k+u_k) (6 shfl); (c) walk capped at 40 iterations;
// stragglers go to a hard-list handled by brute_kernel (exact full scan of
// the 8-pt group vs all M targets), which overwrites their partials.
// Exactness: remaining right targets have x >= exR - BW (bucket-monotone) ->
// d2 >= clamp(exR-BW-px_k)^2 >= gR^2; stop when gR^2 > U >= every point's
// current best. Sentinels (x=+/-1e18, w=1e36) keep u positive-huge and
// force termination; cap + brute pass guarantees exactness regardless.

typedef float float4_t __attribute__((ext_vector_type(4)));

#define NB 1024
#define XLO_BND (-6.0f)
#define XSCALE (NB / 12.0f)
#define BWF (12.0f / NB)   // bucket width
#define PAD 128            // sentinel pad per side per cloud
#define GPTS 8             // points per wave in walk kernel
#define WPB 4              // waves per walk block
#define CAPIT 40           // max walk iterations before deferring to brute

static __device__ __forceinline__ int bucket_of(float x) {
  float f = (x - XLO_BND) * XSCALE;
  f = fminf(fmaxf(f, 0.f), (float)(NB - 1));  // clamp BEFORE cast (fptosi UB)
  return (int)f;
}

// S1: per-cloud LDS histogram + scan + cursors + sentinel pads (8 blocks)
__global__ __launch_bounds__(1024) void hist_scan_kernel(
    const float* __restrict__ pred, const float* __restrict__ target,
    int* __restrict__ bstart, int* __restrict__ gcursor,
    float4_t* __restrict__ sorted, int* __restrict__ hardcnt, int M) {
  int c = blockIdx.x;  // cloud: 2*b + (0=pred,1=target)
  const float* src = ((c & 1) ? target : pred) + (size_t)(c >> 1) * M * 3;
  __shared__ int hist[NB], sc[NB];
  int t = threadIdx.x;
  hist[t] = 0;
  if (c == 0 && t == 0) *hardcnt = 0;
  __syncthreads();
  for (int i = t; i < M; i += 1024) atomicAdd(&hist[bucket_of(src[3 * i])], 1);
  __syncthreads();
  sc[t] = hist[t];
  __syncthreads();
  for (int off = 1; off < NB; off <<= 1) {  // Hillis-Steele inclusive scan
    int v = sc[t];
    if (t >= off) v += sc[t - off];
    __syncthreads();
    sc[t] = v;
    __syncthreads();
  }
  int excl = sc[t] - hist[t];
  bstart[c * (NB + 1) + t] = excl;
  if (t == 0) bstart[c * (NB + 1) + NB] = M;
  gcursor[c * NB + t] = excl;
  float4_t* base = sorted + (size_t)c * (M + 2 * PAD) + PAD;
  if (t < PAD) {  // w = x^2 so expansion-u stays huge-positive at sentinels
    base[-PAD + t] = (float4_t){-1.0e18f, 0.f, 0.f, 1.0e36f};
    base[M + t] = (float4_t){1.0e18f, 0.f, 0.f, 1.0e36f};
  }
}

// S2: scatter into padded sorted layout (64 blocks)
__global__ __launch_bounds__(256) void scatter_kernel(
    const float* __restrict__ pred, const float* __restrict__ target,
    int* __restrict__ gcursor, float4_t* __restrict__ sorted, int M) {
  int chunks = M / 1024;
  int c = blockIdx.x / chunks, chunk = blockIdx.x % chunks;
  const float* src = ((c & 1) ? target : pred) + (size_t)(c >> 1) * M * 3;
  float4_t* base = sorted + (size_t)c * (M + 2 * PAD) + PAD;
  int t = threadIdx.x;
#pragma unroll
  for (int u = 0; u < 4; ++u) {
    int i = chunk * 1024 + t + 256 * u;
    float x = src[3 * i], y = src[3 * i + 1], z = src[3 * i + 2];
    int slot = atomicAdd(&gcursor[c * NB + bucket_of(x)], 1);
    base[slot] = (float4_t){x, y, z, x * x + y * y + z * z};
  }
}

// W: one wave per 8 points; prefetched capped walk, scalar-U exit test
__global__ __launch_bounds__(256) void walk_kernel(
    const float4_t* __restrict__ sorted, const int* __restrict__ bstart,
    float* __restrict__ partial, int* __restrict__ hardlist,
    int* __restrict__ hardcnt, int M) {
  int wavesPerInst = M / GPTS;  // 1024
  int gid = blockIdx.x * WPB + ((int)threadIdx.x >> 6);
  int inst = gid / wavesPerInst;
  int wi = gid % wavesPerInst;
  int b = inst >> 1, dir = inst & 1;
  int cs = 2 * b + dir, cr = 2 * b + (dir ^ 1);
  int cstride = M + 2 * PAD;
  const float4_t* SP = sorted + (size_t)cs * cstride + PAD;
  const float4_t* RP = sorted + (size_t)cr * cstride + PAD;
  int lane = threadIdx.x & 63;

  float ax[GPTS], ay[GPTS], az[GPTS], cm[GPTS], mnu[GPTS];
  float pxmn = 3.0e38f, pxmx = -3.0e38f;
#pragma unroll
  for (int k = 0; k < GPTS; ++k) {  // uniform-address loads (L1 broadcast)
    float4_t p = SP[wi * GPTS + k];
    ax[k] = -2.f * p.x; ay[k] = -2.f * p.y; az[k] = -2.f * p.z;
    cm[k] = p.w;        // |p|^2 (sorted stores w = |.|^2)
    mnu[k] = 1.0e30f;   // shifted-min; sentinel u ~1e36 never wins
    pxmn = fminf(pxmn, p.x);
    pxmx = fmaxf(pxmx, p.x);
  }
  int j0 = bstart[cr * (NB + 1) + bucket_of(-0.25f * (ax[0] + ax[GPTS - 1]))];
  int jr = j0, jl = j0 - 64;
  const int jrmax = M + PAD - 64, jlmin = -PAD;  // clamp => loads always safe
  float4_t qr = RP[min(jr, jrmax) + lane];
  float4_t ql = RP[max(jl, jlmin) + lane];
  bool doneR = false, doneL = false, hard = false;  // wave-uniform
  float exR = -3.0e38f, exL = 3.0e38f;
  int it = 0;
  while (true) {
    if (!doneR) {
      exR = __shfl(qr.x, 63, 64);  // edge of chunk being computed
      float4_t qn = RP[min(jr + 64, jrmax) + lane];  // prefetch next
#pragma unroll
      for (int k = 0; k < GPTS; ++k)  // u = qw - 2 p.q : 3 fma + 1 min
        mnu[k] = fminf(mnu[k],
                       fmaf(ax[k], qr.x, fmaf(ay[k], qr.y,
                            fmaf(az[k], qr.z, qr.w))));
      jr += 64;
      qr = qn;
    }
    if (!doneL) {
      exL = __shfl(ql.x, 0, 64);
      float4_t qn = RP[max(jl - 64, jlmin) + lane];
#pragma unroll
      for (int k = 0; k < GPTS; ++k)
        mnu[k] = fminf(mnu[k],
                       fmaf(ax[k], ql.x, fmaf(ay[k], ql.y,
                            fmaf(az[k], ql.z, ql.w))));
      jl -= 64;
      ql = qn;
    }
    if ((++it & 1) == 0) {  // every 2 rounds: scalar-U reduce + exit test
      float U = 0.f;
#pragma unroll
      for (int k = 0; k < GPTS; ++k) U = fmaxf(U, cm[k] + mnu[k]);
#pragma unroll
      for (int off = 32; off > 0; off >>= 1)
        U = fmaxf(U, __shfl_xor(U, off, 64));
      float gR = fmaxf(exR - pxmx - BWF, 0.f);  // lower bound on remaining
      float gL = fmaxf(pxmn - exL - BWF, 0.f);
      doneR = doneR || (gR * gR > U);
      doneL = doneL || (gL * gL > U);
      if (doneR && doneL) break;
      if (it >= CAPIT) { hard = true; break; }  // defer to brute pass
    }
  }
  // full per-k reduce only once, at exit
#pragma unroll
  for (int k = 0; k < GPTS; ++k)
#pragma unroll
    for (int off = 32; off > 0; off >>= 1)
      mnu[k] = fminf(mnu[k], __shfl_xor(mnu[k], off, 64));
  if (lane == 0) {
    float s = 0.f;
#pragma unroll
    for (int k = 0; k < GPTS; ++k) s += cm[k] + mnu[k];
    partial[gid] = hard ? 0.f : s;
    if (hard) hardlist[atomicAdd(hardcnt, 1)] = gid;
  }
}

// B: exact full-scan for hard groups; overwrites their partials
__global__ __launch_bounds__(256) void brute_kernel(
    const float4_t* __restrict__ sorted, const int* __restrict__ hardlist,
    const int* __restrict__ hardcnt, float* __restrict__ partial, int M) {
  int n = *hardcnt;
  int cstride = M + 2 * PAD;
  __shared__ float red[4][GPTS];
  for (int h = blockIdx.x; h < n; h += gridDim.x) {
    int gid = hardlist[h];
    int wavesPerInst = M / GPTS;
    int inst = gid / wavesPerInst, wi = gid % wavesPerInst;
    int b = inst >> 1, dir = inst & 1;
    const float4_t* SP = sorted + (size_t)(2 * b + dir) * cstride + PAD;
    const float4_t* RP = sorted + (size_t)(2 * b + (dir ^ 1)) * cstride + PAD;
    float ax[GPTS], ay[GPTS], az[GPTS], cm[GPTS], mnu[GPTS];
#pragma unroll
    for (int k = 0; k < GPTS; ++k) {
      float4_t p = SP[wi * GPTS + k];
      ax[k] = -2.f * p.x; ay[k] = -2.f * p.y; az[k] = -2.f * p.z;
      cm[k] = p.w;
      mnu[k] = 1.0e30f;
    }
    for (int j = threadIdx.x; j < M; j += 256) {  // coalesced full scan
      float4_t q = RP[j];
#pragma unroll
      for (int k = 0; k < GPTS; ++k)
        mnu[k] = fminf(mnu[k],
                       fmaf(ax[k], q.x, fmaf(ay[k], q.y,
                            fmaf(az[k], q.z, q.w))));
    }
#pragma unroll
    for (int k = 0; k < GPTS; ++k)
#pragma unroll
      for (int off = 32; off > 0; off >>= 1)
        mnu[k] = fminf(mnu[k], __shfl_xor(mnu[k], off, 64));
    int lane = threadIdx.x & 63, w = threadIdx.x >> 6;
    if (lane == 0)
#pragma unroll
      for (int k = 0; k < GPTS; ++k) red[w][k] = mnu[k];
    __syncthreads();
    if (threadIdx.x == 0) {
      float s = 0.f;
#pragma unroll
      for (int k = 0; k < GPTS; ++k) {
        float m = fminf(fminf(red[0][k], red[1][k]),
                        fminf(red[2][k], red[3][k]));
        s += cm[k] + m;
      }
      partial[gid] = s;
    }
    __syncthreads();  // red[] reuse safety for next h
  }
}

// R: sum partials -> out (direct write; out is re-poisoned each launch)
__global__ __launch_bounds__(256) void reduce_kernel(
    const float* __restrict__ partial, float* __restrict__ out, int n,
    float scale) {
  float s = 0.f;
  for (int i = threadIdx.x; i < n; i += 256) s += partial[i];
  for (int off = 32; off > 0; off >>= 1) s += __shfl_down(s, off, 64);
  __shared__ float ws[4];
  if ((threadIdx.x & 63) == 0) ws[threadIdx.x >> 6] = s;
  __syncthreads();
  if (threadIdx.x == 0) out[0] = (ws[0] + ws[1] + ws[2] + ws[3]) * scale;
}

extern "C" void kernel_launch(void* const* d_in, const int* in_sizes, int n_in,
                              void* d_out, int out_size, void* d_ws,
                              size_t ws_size, hipStream_t stream) {
  const float* pred = (const float*)d_in[0];
  const float* target = (const float*)d_in[1];
  float* out = (float*)d_out;
  const int B = 4;
  const int M = in_sizes[0] / (B * 3);  // 8192

  char* ws = (char*)d_ws;
  float4_t* sorted = (float4_t*)ws;                 // 8*(M+2*PAD)*16 B
  size_t off1 = (size_t)8 * (M + 2 * PAD) * 16;
  int* bstart = (int*)(ws + off1);                  // 8*(NB+1) ints
  size_t off2 = off1 + (size_t)8 * (NB + 1) * 4;
  int* gcursor = (int*)(ws + off2);                 // 8*NB ints
  size_t off3 = off2 + (size_t)8 * NB * 4;
  float* partial = (float*)(ws + off3);             // 8*M/GPTS floats
  size_t off4 = off3 + (size_t)8 * (M / GPTS) * 4;
  int* hardlist = (int*)(ws + off4);                // 8*M/GPTS ints
  size_t off5 = off4 + (size_t)8 * (M / GPTS) * 4;
  int* hardcnt = (int*)(ws + off5);                 // 1 int

  float scale = 1.0f / (float)(B * M);  // sum_all/(B*M) == reference mean

  hist_scan_kernel<<<8, 1024, 0, stream>>>(pred, target, bstart, gcursor,
                                           sorted, hardcnt, M);
  int chunks = 8 * (M / 1024);  // 64
  scatter_kernel<<<chunks, 256, 0, stream>>>(pred, target, gcursor, sorted, M);
  int nwaves = 8 * (M / GPTS);  // 8192
  walk_kernel<<<nwaves / WPB, 256, 0, stream>>>(sorted, bstart, partial,
                                                hardlist, hardcnt, M);
  brute_kernel<<<256, 256, 0, stream>>>(sorted, hardlist, hardcnt, partial, M);
  reduce_kernel<<<1, 256, 0, stream>>>(partial, out, nwaves, scale);
}